// Round 5
// baseline (276.361 us; speedup 1.0000x reference)
//
#include <hip/hip_runtime.h>

// Problem constants
constexpr int N = 4096;   // nodes
constexpr int E = 4096;   // hyperedges
constexpr int F = 128;

// GEMM tiling: per block 64 output-cols (e) or rows (n) x full F; K-split 16.
constexpr int KSPLIT = 16;
constexpr int KEXT   = 4096 / KSPLIT;   // 256 k per block
constexpr int BK     = 64;              // k per chunk
constexpr int NCH    = KEXT / BK;       // 4 chunks

typedef __attribute__((ext_vector_type(8))) short bf16x8;
typedef __attribute__((ext_vector_type(4))) float f32x4;

__device__ __forceinline__ ushort f2bf_rne(float x) {
    union { float f; unsigned u; } v; v.f = x;
    return (ushort)((v.u + 0x7FFFu + ((v.u >> 16) & 1u)) >> 16);
}
// H is exactly {0,1}: truncation is exact.
__device__ __forceinline__ short f2bf_trunc(float x) {
    return (short)(ushort)(__float_as_uint(x) >> 16);
}

__device__ __forceinline__ void gload_lds16(const void* g, void* l) {
    __builtin_amdgcn_global_load_lds(
        (const __attribute__((address_space(1))) void*)g,
        (__attribute__((address_space(3))) void*)l, 16, 0, 0);
}

// Per-wave wait: all outstanding vector-memory (incl. LDS-DMA) retired.
// 0x0F70 = vmcnt(0), expcnt(7)=nowait, lgkmcnt(15)=nowait (gfx9 encoding).
// sched_barrier(0) fences keep the compiler from hoisting ds_reads above it.
__device__ __forceinline__ void wave_vm_drain() {
    __builtin_amdgcn_sched_barrier(0);
    __builtin_amdgcn_s_waitcnt(0x0F70);
    __builtin_amdgcn_sched_barrier(0);
}

// ---------------------------------------------------------------------------
// reciprocal of the diagonals of D_v / D_e
// ---------------------------------------------------------------------------
__global__ void k_recip_diag(const float* __restrict__ Dv,
                             const float* __restrict__ De,
                             float* __restrict__ dv_inv,
                             float* __restrict__ de_inv) {
    int i = blockIdx.x * blockDim.x + threadIdx.x;
    if (i < N) dv_inv[i] = 1.0f / Dv[(size_t)i * (N + 1)];
    if (i < E) de_inv[i] = 1.0f / De[(size_t)i * (E + 1)];
}

// ---------------------------------------------------------------------------
// thetaT[f][n] = bf16( (X@W)[n][f] )   — [128][4096] bf16
// ---------------------------------------------------------------------------
__global__ void k_theta_t(const float* __restrict__ X,
                          const float* __restrict__ W,
                          ushort* __restrict__ thetaT) {
    __shared__ float Xs[8][F];
    const int r0 = blockIdx.x * 8;
    const int t  = threadIdx.x;  // 0..127 = f
    #pragma unroll
    for (int i = 0; i < 8; ++i)
        Xs[i][t] = X[(size_t)(r0 + i) * F + t];
    __syncthreads();
    float acc[8];
    #pragma unroll
    for (int i = 0; i < 8; ++i) acc[i] = 0.0f;
    for (int k = 0; k < F; ++k) {
        const float w = W[k * F + t];
        #pragma unroll
        for (int i = 0; i < 8; ++i) acc[i] += Xs[i][k] * w;
    }
    ushort u[8];
    #pragma unroll
    for (int i = 0; i < 8; ++i) u[i] = f2bf_rne(acc[i]);
    *(uint4*)&thetaT[(size_t)t * N + r0] = *(uint4*)u;
}

// ---------------------------------------------------------------------------
// GEMM1': MT[f][e] (+)= de_inv[e] * sum_n thetaT[f][n] * H[n][e]
//   Barrier-free: each wave stages its private 16-e-wide H slice (double-buf,
//   explicit per-wave vmcnt drain). thetaT fragments straight from global.
// Grid (E/64, KSPLIT); 256 thr = 4 waves; wave -> 16 e-cols x 128 f-rows.
// ---------------------------------------------------------------------------
__global__ __launch_bounds__(256, 4) void k_gemm1(
        const float* __restrict__ Hg,        // [N][E] fp32
        const ushort* __restrict__ thT,      // [F][N] bf16
        const float* __restrict__ de_inv,    // [E]
        float* __restrict__ MTf) {           // [F][E] fp32 (atomic)
    __shared__ float As[4 * 2 * BK * 16];    // 32 KB: per-wave dbuf [n64][e16]
    const int t    = threadIdx.x;
    const int wave = t >> 6;
    const int lane = t & 63;
    const int mm   = lane & 15;
    const int quad = lane >> 4;
    const int e0   = blockIdx.x * 64;
    const int ew   = e0 + wave * 16;         // this wave's 16 e-columns
    const int kb   = blockIdx.y * KEXT;

    float* base0 = &As[(wave * 2 + 0) * BK * 16];
    float* base1 = &As[(wave * 2 + 1) * BK * 16];

    f32x4 acc[8];
    #pragma unroll
    for (int ft = 0; ft < 8; ++ft) acc[ft] = (f32x4){0.f, 0.f, 0.f, 0.f};

    // stage chunk ch: 64 n-rows x 64 B (16 e fp32) per row
    auto stage = [&](int ch, float* dst) {
        const int kg = kb + ch * BK;
        #pragma unroll
        for (int i = 0; i < 4; ++i) {
            const int row = i * 16 + (lane >> 2);    // n-local 0..63
            const int so  = (lane & 3) * 16;         // byte offset in 64-B row
            gload_lds16((const char*)Hg + ((size_t)(kg + row) * E + ew) * 4 + so,
                        (char*)dst + i * 1024 + lane * 16);
        }
    };

    stage(0, base0);
    #pragma unroll
    for (int ch = 0; ch < NCH; ++ch) {
        const float* cur = (ch & 1) ? base1 : base0;
        float* nxt       = (ch & 1) ? base0 : base1;
        const int kg = kb + ch * BK;
        wave_vm_drain();                         // cur's DMA retired
        // LDS column fragments (H): 4-way bank conflict (1.58x), cheap
        bf16x8 hb[2];
        #pragma unroll
        for (int kk = 0; kk < 2; ++kk) {
            const int ko = kk * 32 + quad * 8;       // n-local base
            #pragma unroll
            for (int j = 0; j < 8; ++j)
                hb[kk][j] = f2bf_trunc(cur[(ko + j) * 16 + mm]);
        }
        if (ch + 1 < NCH) stage(ch + 1, nxt);    // prefetch overlaps below
        #pragma unroll
        for (int kk = 0; kk < 2; ++kk) {
            const int ko = kg + kk * 32 + quad * 8;
            bf16x8 af[8];
            #pragma unroll
            for (int ft = 0; ft < 8; ++ft)
                af[ft] = *(const bf16x8*)&thT[(size_t)(ft * 16 + mm) * N + ko];
            #pragma unroll
            for (int ft = 0; ft < 8; ++ft)
                acc[ft] = __builtin_amdgcn_mfma_f32_16x16x32_bf16(
                              af[ft], hb[kk], acc[ft], 0, 0, 0);
        }
    }
    // Epilogue: D row = f (ft*16 + quad*4+r), col = e (mm); scale de_inv[e]
    const float s = de_inv[ew + mm];
    #pragma unroll
    for (int ft = 0; ft < 8; ++ft) {
        const int row = ft * 16 + quad * 4;
        #pragma unroll
        for (int r = 0; r < 4; ++r)
            atomicAdd(&MTf[(size_t)(row + r) * E + ew + mm], acc[ft][r] * s);
    }
}

// ---------------------------------------------------------------------------
// streaming cast: MTb[f][e] = bf16(MTf[f][e])
// ---------------------------------------------------------------------------
__global__ void k_castMT(const float* __restrict__ Mf,
                         ushort* __restrict__ Mb) {
    const int i = (blockIdx.x * 256 + threadIdx.x) * 8;
    const float4 v0 = *(const float4*)&Mf[i];
    const float4 v1 = *(const float4*)&Mf[i + 4];
    ushort u[8];
    u[0] = f2bf_rne(v0.x); u[1] = f2bf_rne(v0.y);
    u[2] = f2bf_rne(v0.z); u[3] = f2bf_rne(v0.w);
    u[4] = f2bf_rne(v1.x); u[5] = f2bf_rne(v1.y);
    u[6] = f2bf_rne(v1.z); u[7] = f2bf_rne(v1.w);
    *(uint4*)&Mb[i] = *(uint4*)u;
}

// ---------------------------------------------------------------------------
// GEMM2: out[n][f] (+)= dv_inv[n] * sum_e H[n][e] * MT[f][e]
//   Per-wave [m16][k64] H staging with XOR-swizzled global source so the
//   b128 LDS reads are 2-way conflict-free. MT fragments from global.
// Grid (N/64, KSPLIT); wave -> 16 n-rows x 128 f.
// ---------------------------------------------------------------------------
__global__ __launch_bounds__(256, 4) void k_gemm2(
        const float* __restrict__ Hg,        // [N][E] fp32
        const ushort* __restrict__ MTb,      // [F][E] bf16
        const float* __restrict__ dv_inv,    // [N]
        float* __restrict__ Out) {           // [N][F] fp32 (atomic)
    __shared__ float As[4 * 2 * 16 * BK];    // 32 KB; [m][seg^m] swizzled
    const int t    = threadIdx.x;
    const int wave = t >> 6;
    const int lane = t & 63;
    const int mm   = lane & 15;
    const int quad = lane >> 4;
    const int n0   = blockIdx.x * 64;
    const int nw   = n0 + wave * 16;         // this wave's 16 n-rows
    const int kb   = blockIdx.y * KEXT;

    float* base0 = &As[(wave * 2 + 0) * 16 * BK];
    float* base1 = &As[(wave * 2 + 1) * 16 * BK];

    f32x4 acc[8];
    #pragma unroll
    for (int fs = 0; fs < 8; ++fs) acc[fs] = (f32x4){0.f, 0.f, 0.f, 0.f};

    // stage chunk: 16 m-rows x 256 B; seg s of row m lands at LDS slot s^m
    auto stage = [&](int ch, float* dst) {
        const int kg = kb + ch * BK;
        #pragma unroll
        for (int i = 0; i < 4; ++i) {
            const int m = i * 4 + (lane >> 4);       // m-local 0..15
            const int q = lane & 15;                 // LDS seg slot
            const int s = q ^ m;                     // logical 16-B segment
            gload_lds16((const char*)Hg + ((size_t)(nw + m) * E + kg) * 4 + s * 16,
                        (char*)dst + i * 1024 + lane * 16);
        }
    };

    stage(0, base0);
    #pragma unroll
    for (int ch = 0; ch < NCH; ++ch) {
        const float* cur = (ch & 1) ? base1 : base0;
        float* nxt       = (ch & 1) ? base0 : base1;
        const int kg = kb + ch * BK;
        wave_vm_drain();                         // cur's DMA retired
        // A fragments from swizzled LDS: two b128 per kk, 2-way conflict
        bf16x8 ha[2];
        #pragma unroll
        for (int kk = 0; kk < 2; ++kk) {
            const int ko = kk * 32 + quad * 8;       // e-local fp32 base
            const int s0 = ko >> 2;                  // 16-B segment (even)
            const float4 v0 = *(const float4*)((const char*)cur + mm * 256 + ((s0 ^ mm) * 16));
            const float4 v1 = *(const float4*)((const char*)cur + mm * 256 + (((s0 + 1) ^ mm) * 16));
            ha[kk][0] = f2bf_trunc(v0.x); ha[kk][1] = f2bf_trunc(v0.y);
            ha[kk][2] = f2bf_trunc(v0.z); ha[kk][3] = f2bf_trunc(v0.w);
            ha[kk][4] = f2bf_trunc(v1.x); ha[kk][5] = f2bf_trunc(v1.y);
            ha[kk][6] = f2bf_trunc(v1.z); ha[kk][7] = f2bf_trunc(v1.w);
        }
        if (ch + 1 < NCH) stage(ch + 1, nxt);    // prefetch overlaps below
        #pragma unroll
        for (int kk = 0; kk < 2; ++kk) {
            const int ko = kg + kk * 32 + quad * 8;
            bf16x8 bf[8];
            #pragma unroll
            for (int fs = 0; fs < 8; ++fs)
                bf[fs] = *(const bf16x8*)&MTb[(size_t)(fs * 16 + mm) * E + ko];
            #pragma unroll
            for (int fs = 0; fs < 8; ++fs)
                acc[fs] = __builtin_amdgcn_mfma_f32_16x16x32_bf16(
                              ha[kk], bf[fs], acc[fs], 0, 0, 0);
        }
    }
    // Epilogue: D row = n (quad*4+r), col = f (fs*16+mm); scale dv_inv[n]
    const int rowb = nw + quad * 4;
    const float4 rs = *(const float4*)&dv_inv[rowb];
    const float rsa[4] = {rs.x, rs.y, rs.z, rs.w};
    #pragma unroll
    for (int fs = 0; fs < 8; ++fs) {
        const int col = fs * 16 + mm;
        #pragma unroll
        for (int r = 0; r < 4; ++r)
            atomicAdd(&Out[(size_t)(rowb + r) * F + col], acc[fs][r] * rsa[r]);
    }
}

// ---------------------------------------------------------------------------
extern "C" void kernel_launch(void* const* d_in, const int* in_sizes, int n_in,
                              void* d_out, int out_size, void* d_ws, size_t ws_size,
                              hipStream_t stream) {
    const float* X  = (const float*)d_in[0];   // [N,128]
    const float* H  = (const float*)d_in[1];   // [N,E] fp32 (binary)
    const float* Dv = (const float*)d_in[2];   // [N,N]
    const float* De = (const float*)d_in[3];   // [E,E]
    const float* W  = (const float*)d_in[4];   // [128,128]
    float* out = (float*)d_out;                // [N,128]
    char* ws = (char*)d_ws;

    // workspace layout (~4.03 MB)
    float*  MTf    = (float*)ws;                                   // 2 MB  [f][e] fp32
    ushort* MTbf   = (ushort*)(ws + (size_t)2 * 1024 * 1024);      // 1 MB  [f][e] bf16
    ushort* thetaT = (ushort*)(ws + (size_t)3 * 1024 * 1024);      // 1 MB  [f][n] bf16
    float*  dv_inv = (float*)(ws + (size_t)4 * 1024 * 1024);       // 16 KB
    float*  de_inv = dv_inv + N;                                   // 16 KB

    hipMemsetAsync(MTf, 0, (size_t)F * E * sizeof(float), stream);
    hipMemsetAsync(out, 0, (size_t)N * F * sizeof(float), stream);

    k_recip_diag<<<dim3(N / 256), dim3(256), 0, stream>>>(Dv, De, dv_inv, de_inv);
    k_theta_t<<<dim3(N / 8), dim3(128), 0, stream>>>(X, W, thetaT);
    // GEMM1': MT[f][e] = de_inv[e] * sum_n thetaT[f][n] * H[n][e]
    k_gemm1<<<dim3(E / 64, KSPLIT), dim3(256), 0, stream>>>(H, thetaT, de_inv, MTf);
    k_castMT<<<dim3(F * E / 8 / 256), dim3(256), 0, stream>>>(MTf, MTbf);
    // GEMM2: out[n][f] = dv_inv[n] * sum_e H[n][e] * MT[f][e]
    k_gemm2<<<dim3(N / 64, KSPLIT), dim3(256), 0, stream>>>(H, MTbf, dv_inv, out);
}